// Round 1
// baseline (765.792 us; speedup 1.0000x reference)
//
#include <hip/hip_runtime.h>
#include <cstdint>

// SparseMLP: out = relu(relu(x@W1^T+b1)@W2^T+b2)@W3^T+b3
// M = N = K = 4096 for every layer. fp32 in/out; fp16 MFMA internally
// (threshold = 2% of max|ref| admits it; fp16 est. max err ~70 vs 476).
//
// GEMM = m97-ladder structure (128x128 tile, BK=32, global_load_lds w=16,
// 16x16x32 MFMA, 4x4 acc per wave, 2-barrier K-loop). Measured 874 TF on
// this shape for bf16; f16 runs at the same MFMA rate.

#define MATN 4096

typedef _Float16 half8 __attribute__((ext_vector_type(8)));
typedef float f32x4 __attribute__((ext_vector_type(4)));

// async global->LDS, 16B per lane. LDS dest = wave-uniform base + lane*16.
__device__ __forceinline__ void glds16(const void* g, const void* l) {
    __builtin_amdgcn_global_load_lds(
        (const __attribute__((address_space(1))) char*)(uintptr_t)g,
        (__attribute__((address_space(3))) char*)(uintptr_t)l,
        16, 0, 0);
}

// fp32 -> fp16 convert, 8 elems/thread (32B read, 16B write per lane)
__global__ __launch_bounds__(256)
void cvt_f16(const float* __restrict__ in, _Float16* __restrict__ out) {
    size_t i = ((size_t)blockIdx.x * 256 + threadIdx.x) * 8;
    const float4* p = (const float4*)(in + i);
    float4 a = p[0];
    float4 b = p[1];
    half8 o;
    o[0] = (_Float16)a.x; o[1] = (_Float16)a.y;
    o[2] = (_Float16)a.z; o[3] = (_Float16)a.w;
    o[4] = (_Float16)b.x; o[5] = (_Float16)b.y;
    o[6] = (_Float16)b.z; o[7] = (_Float16)b.w;
    *(half8*)(out + i) = o;
}

// C[m][n] = sum_k A[m][k] * B[n][k] + bias[n]  (optional ReLU)
// A: [4096][4096] f16 row-major (K-contig). B: [4096][4096] f16 row-major
// (K-contig, i.e. B^T input). OutT = _Float16 (hidden) or float (final).
template <bool RELU, typename OutT>
__global__ __launch_bounds__(256)
void gemm_bt(const _Float16* __restrict__ A, const _Float16* __restrict__ B,
             const float* __restrict__ bias, OutT* __restrict__ C) {
    __shared__ _Float16 sA[128 * 32];  // [row][k], 64B rows
    __shared__ _Float16 sB[128 * 32];  // [n][k]

    const int tid  = threadIdx.x;
    const int lane = tid & 63;
    const int w    = tid >> 6;   // 4 waves
    const int wm   = w >> 1;     // 2x2 wave grid over 128x128
    const int wn   = w & 1;
    const int l16  = lane & 15;
    const int kq   = lane >> 4;  // 0..3 (k-quad)

    const int tileM = blockIdx.y * 128;
    const int tileN = blockIdx.x * 128;

    f32x4 acc[4][4];
#pragma unroll
    for (int i = 0; i < 4; ++i)
#pragma unroll
        for (int j = 0; j < 4; ++j)
            acc[i][j] = f32x4{0.f, 0.f, 0.f, 0.f};

    // staging: tile is 128x32 f16 = 8KB; 256 threads * 2 loads * 16B.
    // flat elem e = (load*256 + tid)*8 ; row = e>>5, col = e&31.
    const int e0 = tid * 8;
    const int r0 = e0 >> 5;
    const int c0 = e0 & 31;
    const int r1 = r0 + 64;          // second load: e += 2048 -> row += 64

    const _Float16* Ab = A + (size_t)tileM * MATN;
    const _Float16* Bb = B + (size_t)tileN * MATN;

    // wave-uniform LDS bases (builtin adds lane*16)
    char* sAb0 = (char*)sA + w * 64 * 16;
    char* sAb1 = sAb0 + 256 * 16;
    char* sBb0 = (char*)sB + w * 64 * 16;
    char* sBb1 = sBb0 + 256 * 16;

    for (int k0 = 0; k0 < MATN; k0 += 32) {
        glds16(Ab + (size_t)r0 * MATN + k0 + c0, sAb0);
        glds16(Ab + (size_t)r1 * MATN + k0 + c0, sAb1);
        glds16(Bb + (size_t)r0 * MATN + k0 + c0, sBb0);
        glds16(Bb + (size_t)r1 * MATN + k0 + c0, sBb1);
        __syncthreads();  // compiler emits vmcnt(0) drain before s_barrier

        half8 af[4], bf[4];
#pragma unroll
        for (int mi = 0; mi < 4; ++mi)
            af[mi] = *(const half8*)(sA + (wm * 64 + mi * 16 + l16) * 32 + kq * 8);
#pragma unroll
        for (int ni = 0; ni < 4; ++ni)
            bf[ni] = *(const half8*)(sB + (wn * 64 + ni * 16 + l16) * 32 + kq * 8);

#pragma unroll
        for (int mi = 0; mi < 4; ++mi)
#pragma unroll
            for (int ni = 0; ni < 4; ++ni)
                acc[mi][ni] = __builtin_amdgcn_mfma_f32_16x16x32_f16(
                    af[mi], bf[ni], acc[mi][ni], 0, 0, 0);
        __syncthreads();  // protect LDS before next stage
    }

    // epilogue: C/D layout col = lane&15, row = (lane>>4)*4 + reg (m89)
#pragma unroll
    for (int ni = 0; ni < 4; ++ni) {
        const int gn = tileN + wn * 64 + ni * 16 + l16;
        const float bv = bias[gn];
#pragma unroll
        for (int mi = 0; mi < 4; ++mi) {
            const int gm = tileM + wm * 64 + mi * 16 + kq * 4;
#pragma unroll
            for (int r = 0; r < 4; ++r) {
                float v = acc[mi][ni][r] + bv;
                if (RELU) v = v > 0.f ? v : 0.f;
                C[(size_t)(gm + r) * MATN + gn] = (OutT)v;
            }
        }
    }
}

extern "C" void kernel_launch(void* const* d_in, const int* in_sizes, int n_in,
                              void* d_out, int out_size, void* d_ws, size_t ws_size,
                              hipStream_t stream) {
    const float* x  = (const float*)d_in[0];
    const float* W1 = (const float*)d_in[1];
    const float* b1 = (const float*)d_in[2];
    const float* W2 = (const float*)d_in[3];
    const float* b2 = (const float*)d_in[4];
    const float* W3 = (const float*)d_in[5];
    const float* b3 = (const float*)d_in[6];
    float* out = (float*)d_out;

    const size_t MAT = (size_t)MATN * MATN;  // 16.78M elems
    _Float16* xb = (_Float16*)d_ws;                          // 32MB (reused as h2)
    _Float16* wb = (_Float16*)((char*)d_ws + MAT * 2);       // 32MB (per-layer W)
    _Float16* h1 = (_Float16*)((char*)d_ws + MAT * 4);       // 32MB
    _Float16* h2 = xb;

    const int cblocks = (int)(MAT / (8 * 256));  // 8192
    dim3 ggrid(MATN / 128, MATN / 128);          // 32x32

    cvt_f16<<<cblocks, 256, 0, stream>>>(x, xb);
    cvt_f16<<<cblocks, 256, 0, stream>>>(W1, wb);
    gemm_bt<true, _Float16><<<ggrid, 256, 0, stream>>>(xb, wb, b1, h1);

    cvt_f16<<<cblocks, 256, 0, stream>>>(W2, wb);
    gemm_bt<true, _Float16><<<ggrid, 256, 0, stream>>>(h1, wb, b2, h2);

    cvt_f16<<<cblocks, 256, 0, stream>>>(W3, wb);
    gemm_bt<false, float><<<ggrid, 256, 0, stream>>>(h2, wb, b3, out);
}

// Round 2
// 691.120 us; speedup vs baseline: 1.1080x; 1.1080x over previous
//
#include <hip/hip_runtime.h>
#include <cstdint>

// SparseMLP: out = relu(relu(x@W1^T+b1)@W2^T+b2)@W3^T+b3
// M = N = K = 4096 per layer. fp32 in/out; fp16 MFMA internally.
//
// R2 changes vs R1 (719 TF/GEMM, occ 23.7%, 1.7e7 bank conflicts):
//  - __launch_bounds__(256,4): force VGPR+AGPR <= 128 -> 4 waves/SIMD
//    -> 4 blocks/CU (R1 was stuck at 2: 80+64=144 regs > 128 bucket).
//  - XOR k-chunk swizzle (slot = kq ^ ((row>>1)&3)) so ds_read_b128
//    fragment reads spread over all 8 bank-groups (2-way = free) instead
//    of 8-way conflicts. global_load_lds can't pad, so we permute which
//    global 16B chunk lands in each LDS slot and invert at read time.

#define MATN 4096

typedef _Float16 half8 __attribute__((ext_vector_type(8)));
typedef float f32x4 __attribute__((ext_vector_type(4)));

// async global->LDS, 16B/lane. LDS dest = wave-uniform base + lane*16.
__device__ __forceinline__ void glds16(const void* g, const void* l) {
    __builtin_amdgcn_global_load_lds(
        (const __attribute__((address_space(1))) char*)(uintptr_t)g,
        (__attribute__((address_space(3))) char*)(uintptr_t)l,
        16, 0, 0);
}

// fp32 -> fp16 convert, 8 elems/thread (32B read, 16B write per lane)
__global__ __launch_bounds__(256)
void cvt_f16(const float* __restrict__ in, _Float16* __restrict__ out) {
    size_t i = ((size_t)blockIdx.x * 256 + threadIdx.x) * 8;
    const float4* p = (const float4*)(in + i);
    float4 a = p[0];
    float4 b = p[1];
    half8 o;
    o[0] = (_Float16)a.x; o[1] = (_Float16)a.y;
    o[2] = (_Float16)a.z; o[3] = (_Float16)a.w;
    o[4] = (_Float16)b.x; o[5] = (_Float16)b.y;
    o[6] = (_Float16)b.z; o[7] = (_Float16)b.w;
    *(half8*)(out + i) = o;
}

// C[m][n] = sum_k A[m][k]*B[n][k] + bias[n] (optional ReLU).
// A,B: [4096][4096] f16 row-major (K-contig). 128x128 tile, BK=32,
// 2x2 waves x 4x4 MFMA(16x16x32) per wave.
template <bool RELU, typename OutT>
__global__ __launch_bounds__(256, 4)
void gemm_bt(const _Float16* __restrict__ A, const _Float16* __restrict__ B,
             const float* __restrict__ bias, OutT* __restrict__ C) {
    __shared__ _Float16 sA[128 * 32];  // [row][slot-swizzled k], 64B rows
    __shared__ _Float16 sB[128 * 32];

    const int tid  = threadIdx.x;
    const int lane = tid & 63;
    const int w    = tid >> 6;   // 4 waves
    const int wm   = w >> 1;     // 2x2 wave grid over 128x128
    const int wn   = w & 1;
    const int l16  = lane & 15;
    const int kq   = lane >> 4;  // 0..3 (k-quad)

    const int tileM = blockIdx.y * 128;
    const int tileN = blockIdx.x * 128;

    f32x4 acc[4][4] = {};

    // --- staging: thread t's 16B lands at LDS flat byte t*16 = row (t>>2),
    // slot (t&3). Swizzle: LDS slot s of row r holds global k-chunk
    // s ^ ((r>>1)&3). Here (r>>1)&3 = (t>>3)&3, same for the +64-row load.
    const int r0 = tid >> 2;                        // 0..63
    const int gc = ((tid & 3) ^ ((tid >> 3) & 3)) * 8;  // swizzled k-offset

    const _Float16* Ap0 = A + (size_t)(tileM + r0) * MATN + gc;
    const _Float16* Ap1 = Ap0 + (size_t)64 * MATN;
    const _Float16* Bp0 = B + (size_t)(tileN + r0) * MATN + gc;
    const _Float16* Bp1 = Bp0 + (size_t)64 * MATN;

    char* sAb0 = (char*)sA + w * 1024;   // wave-uniform LDS bases
    char* sAb1 = sAb0 + 4096;
    char* sBb0 = (char*)sB + w * 1024;
    char* sBb1 = sBb0 + 4096;

    // --- fragment read bases. row = (wm*64 + mi*16 + l16); the swizzle
    // term ((row>>1)&3) reduces to ((l16>>1)&3), mi-independent -> one
    // base pointer + immediate offsets (mi*1024B).
    const int slot = kq ^ ((l16 >> 1) & 3);
    const _Float16* rA = sA + (wm * 64 + l16) * 32 + slot * 8;
    const _Float16* rB = sB + (wn * 64 + l16) * 32 + slot * 8;

    for (int k0 = 0; k0 < MATN; k0 += 32) {
        glds16(Ap0, sAb0);
        glds16(Ap1, sAb1);
        glds16(Bp0, sBb0);
        glds16(Bp1, sBb1);
        Ap0 += 32; Ap1 += 32; Bp0 += 32; Bp1 += 32;
        __syncthreads();

        half8 af[4], bf[4];
#pragma unroll
        for (int mi = 0; mi < 4; ++mi)
            af[mi] = *(const half8*)(rA + mi * 512);
#pragma unroll
        for (int ni = 0; ni < 4; ++ni)
            bf[ni] = *(const half8*)(rB + ni * 512);

#pragma unroll
        for (int mi = 0; mi < 4; ++mi)
#pragma unroll
            for (int ni = 0; ni < 4; ++ni)
                acc[mi][ni] = __builtin_amdgcn_mfma_f32_16x16x32_f16(
                    af[mi], bf[ni], acc[mi][ni], 0, 0, 0);
        __syncthreads();
    }

    // epilogue: C/D layout col = lane&15, row = (lane>>4)*4 + reg (m89)
#pragma unroll
    for (int ni = 0; ni < 4; ++ni) {
        const int gn = tileN + wn * 64 + ni * 16 + l16;
        const float bv = bias[gn];
#pragma unroll
        for (int mi = 0; mi < 4; ++mi) {
            const int gm = tileM + wm * 64 + mi * 16 + kq * 4;
#pragma unroll
            for (int r = 0; r < 4; ++r) {
                float v = acc[mi][ni][r] + bv;
                if (RELU) v = v > 0.f ? v : 0.f;
                C[(size_t)(gm + r) * MATN + gn] = (OutT)v;
            }
        }
    }
}

extern "C" void kernel_launch(void* const* d_in, const int* in_sizes, int n_in,
                              void* d_out, int out_size, void* d_ws, size_t ws_size,
                              hipStream_t stream) {
    const float* x  = (const float*)d_in[0];
    const float* W1 = (const float*)d_in[1];
    const float* b1 = (const float*)d_in[2];
    const float* W2 = (const float*)d_in[3];
    const float* b2 = (const float*)d_in[4];
    const float* W3 = (const float*)d_in[5];
    const float* b3 = (const float*)d_in[6];
    float* out = (float*)d_out;

    const size_t MAT = (size_t)MATN * MATN;  // 16.78M elems
    _Float16* xb = (_Float16*)d_ws;                     // 32MB (reused as h2)
    _Float16* wb = (_Float16*)((char*)d_ws + MAT * 2);  // 32MB (per-layer W)
    _Float16* h1 = (_Float16*)((char*)d_ws + MAT * 4);  // 32MB
    _Float16* h2 = xb;

    const int cblocks = (int)(MAT / (8 * 256));  // 8192
    dim3 ggrid(MATN / 128, MATN / 128);          // 32x32

    cvt_f16<<<cblocks, 256, 0, stream>>>(x, xb);
    cvt_f16<<<cblocks, 256, 0, stream>>>(W1, wb);
    gemm_bt<true, _Float16><<<ggrid, 256, 0, stream>>>(xb, wb, b1, h1);

    cvt_f16<<<cblocks, 256, 0, stream>>>(W2, wb);
    gemm_bt<true, _Float16><<<ggrid, 256, 0, stream>>>(h1, wb, b2, h2);

    cvt_f16<<<cblocks, 256, 0, stream>>>(W3, wb);
    gemm_bt<false, float><<<ggrid, 256, 0, stream>>>(h2, wb, b3, out);
}